// Round 9
// baseline (153.530 us; speedup 1.0000x reference)
//
#include <hip/hip_runtime.h>

// Problem constants: B=8, N_IN=256, N=8192, D=64, K=512
#define NIN    256
#define NCOL   8192
#define DDIM   64
#define KCODES 512
#define ZQ_ELEMS (8ull * 64ull * 8192ull)    // zq floats; hist follows

// ---------------------------------------------------------------------------
// Prep: Wt[i][d] = W[d][i] (conv s_loads contiguous); embT[d][k] = emb[k][d]
// (search s_loads contiguous in k); emb_sq[k] = ||emb[k]||^2 (ascending-d,
// bit-exact vs prior rounds); hist_out = ind_hist (re-init every call).
// ---------------------------------------------------------------------------
__global__ __launch_bounds__(256) void vq_prep(const float* __restrict__ W,
                                               const float* __restrict__ emb,
                                               const float* __restrict__ ind_hist,
                                               float* __restrict__ Wt,
                                               float* __restrict__ embT,
                                               float* __restrict__ emb_sq,
                                               float* __restrict__ hist_out)
{
    const int t = blockIdx.x * 256 + threadIdx.x;   // t < 32768
    if (t < NIN * DDIM) {
        int i = t >> 6;
        int d = t & 63;
        Wt[t] = W[d * NIN + i];
    }
    {
        int d = t >> 9;          // 0..63
        int k = t & 511;         // 0..511
        embT[t] = emb[k * DDIM + d];
    }
    if (t < KCODES) {
        const float* __restrict__ ek = emb + t * DDIM;
        float s = 0.f;
        #pragma unroll
        for (int d = 0; d < DDIM; ++d) s = fmaf(ek[d], ek[d], s);
        emb_sq[t] = s;
        hist_out[t] = ind_hist[t];
    }
}

// ---------------------------------------------------------------------------
// Main fused kernel: block = 512 threads / 8 waves, owns 64 columns.
// 1024 blocks -> 4 blocks/CU = 2048 thr/CU = 32 waves/CU = 8 waves/SIMD
// (round 8 had 4/SIMD and 43% stall; this doubles latency hiding).
//  conv   : wave w computes d-slice [8w,8w+8) for 64 cols (lane=col,
//           Wt s_load, ascending-i fmaf — bit-identical to rounds 1-8).
//           Stores to LDS transpose tile (stride 65: b32 conflict-free).
//  search : wave w owns k-eighth [64w,64w+64), k-tiled by 32.
//           Per tile: 8 static d-chunks of 8: {8 ds_read_b32 -> zd[8],
//           then 8 x 32 reg-reg FMAs; emb operand = wave-uniform s_load of
//           embT[d][kt..kt+32)}. 64 LDS reads / 2048 FMAs per tile (1/32).
//           ALL register-array indices compile-time constant (rule #20 —
//           round 7's runtime-indexed ze[] went to scratch: 165 MB FETCH).
//           acc-chain dependence fixes ascending-d order -> bit-exact dist.
//  merge  : 8 per-wave candidates via LDS, ascending-w strict-< scan
//           == jnp.argmin first-min tie-break.
//  epilog : wave w writes zq d-slice [8w,8w+8); 1 hist atomic per column.
// VGPR budget: launch_bounds(512,8) caps at 64; inner live set is
// acc[32]+zd[8]+misc ~= 50 (round 8 measured 52 with zd[16]).
// ---------------------------------------------------------------------------
__global__ __launch_bounds__(512, 8) void vq_main(const float* __restrict__ z,
                                                  const float* __restrict__ Wt,
                                                  const float* __restrict__ emb,
                                                  const float* __restrict__ embT,
                                                  const float* __restrict__ emb_sq,
                                                  float* __restrict__ out,
                                                  float* __restrict__ hist)
{
    __shared__ float ze_lds[64][DDIM + 1];   // stride 65: b32 conflict-free
    __shared__ float bw_lds[8][64];
    __shared__ int   bk_lds[8][64];

    const int tid = threadIdx.x;
    const int cl  = tid & 63;                                   // column (lane)
    const int w   = __builtin_amdgcn_readfirstlane(tid >> 6);   // wave id 0..7
    const int C   = blockIdx.x * 64 + cl;
    const int b   = C >> 13;
    const int n   = C & (NCOL - 1);

    // ---------------- conv phase: wave w -> d-slice [8w, 8w+8) -------------
    {
        const float* __restrict__ zp = z + (size_t)b * NIN * NCOL + n;
        const float* __restrict__ wp = Wt + w * 8;

        float acc[8];
        #pragma unroll
        for (int j = 0; j < 8; ++j) acc[j] = 0.f;

        for (int i = 0; i < NIN; i += 4) {
            float z0 = zp[(size_t)(i + 0) * NCOL];
            float z1 = zp[(size_t)(i + 1) * NCOL];
            float z2 = zp[(size_t)(i + 2) * NCOL];
            float z3 = zp[(size_t)(i + 3) * NCOL];
            const float* __restrict__ w0 = wp + (size_t)(i + 0) * DDIM;  // s_load
            const float* __restrict__ w1 = wp + (size_t)(i + 1) * DDIM;
            const float* __restrict__ w2 = wp + (size_t)(i + 2) * DDIM;
            const float* __restrict__ w3 = wp + (size_t)(i + 3) * DDIM;
            #pragma unroll
            for (int j = 0; j < 8; ++j) {
                float a = acc[j];
                a = fmaf(w0[j], z0, a);   // ascending i: bit-exact
                a = fmaf(w1[j], z1, a);
                a = fmaf(w2[j], z2, a);
                a = fmaf(w3[j], z3, a);
                acc[j] = a;
            }
        }
        #pragma unroll
        for (int j = 0; j < 8; ++j) ze_lds[cl][w * 8 + j] = acc[j];
    }
    __syncthreads();

    // ---------------- zesq: ascending-d chain (bit-exact) ------------------
    float zesq = 0.f;
    #pragma unroll
    for (int d = 0; d < DDIM; ++d) {
        float zd = ze_lds[cl][d];
        zesq = fmaf(zd, zd, zesq);
    }

    // ---------------- search: wave w owns k in [64w, 64w+64) ---------------
    const int k0 = w * (KCODES / 8);
    float best  = 3.4e38f;
    int   bestk = k0;

    for (int t2 = 0; t2 < 2; ++t2) {                  // 2 k-tiles of 32
        const int kt = k0 + t2 * 32;

        float acc[32];
        #pragma unroll
        for (int kk = 0; kk < 32; ++kk) acc[kk] = 0.f;

        #pragma unroll
        for (int dc = 0; dc < 8; ++dc) {              // 8 static d-chunks of 8
            float zd[8];
            #pragma unroll
            for (int j = 0; j < 8; ++j)
                zd[j] = ze_lds[cl][dc * 8 + j];       // static idx: VGPR

            #pragma unroll
            for (int j = 0; j < 8; ++j) {
                const float* __restrict__ ep =
                    embT + (size_t)(dc * 8 + j) * KCODES + kt;  // s_load
                #pragma unroll
                for (int kk = 0; kk < 32; ++kk)
                    acc[kk] = fmaf(ep[kk], zd[j], acc[kk]);  // ascending d
            }
        }

        #pragma unroll
        for (int kk = 0; kk < 32; ++kk) {
            const int k = kt + kk;
            float dist = (zesq + emb_sq[k]) - 2.0f * acc[kk];  // ref order
            if (dist < best) { best = dist; bestk = k; }       // first-min
        }
    }
    bw_lds[w][cl] = best;
    bk_lds[w][cl] = bestk;
    __syncthreads();

    // ---------------- merge 8 candidates (ascending w, strict <) -----------
    float fb = bw_lds[0][cl];
    int   fk = bk_lds[0][cl];
    #pragma unroll
    for (int ww = 1; ww < 8; ++ww) {
        float v = bw_lds[ww][cl];
        int  kv = bk_lds[ww][cl];
        if (v < fb) { fb = v; fk = kv; }
    }

    // ---------------- histogram: one atomic per column ---------------------
    if (w == 0) atomicAdd(hist + fk, 1.0f);

    // ---------------- straight-through output: wave w writes d-slice [8w,8w+8)
    const float4* __restrict__ eb =
        reinterpret_cast<const float4*>(emb + (size_t)fk * DDIM) + w * 2;
    float* __restrict__ op = out + ((size_t)b * DDIM + w * 8) * NCOL + n;
    #pragma unroll
    for (int v = 0; v < 2; ++v) {
        float4 e = eb[v];
        float z0 = ze_lds[cl][w * 8 + 4 * v + 0];   // LDS: static indices
        float z1 = ze_lds[cl][w * 8 + 4 * v + 1];
        float z2 = ze_lds[cl][w * 8 + 4 * v + 2];
        float z3 = ze_lds[cl][w * 8 + 4 * v + 3];
        op[(size_t)(4 * v + 0) * NCOL] = z0 + (e.x - z0);
        op[(size_t)(4 * v + 1) * NCOL] = z1 + (e.y - z1);
        op[(size_t)(4 * v + 2) * NCOL] = z2 + (e.z - z2);
        op[(size_t)(4 * v + 3) * NCOL] = z3 + (e.w - z3);
    }
}

// ---------------------------------------------------------------------------
extern "C" void kernel_launch(void* const* d_in, const int* in_sizes, int n_in,
                              void* d_out, int out_size, void* d_ws, size_t ws_size,
                              hipStream_t stream)
{
    const float* z        = (const float*)d_in[0];  // (8, 256, 8192)
    const float* W        = (const float*)d_in[1];  // (64, 256)
    const float* emb      = (const float*)d_in[2];  // (512, 64)
    const float* ind_hist = (const float*)d_in[3];  // (512,)

    float* out  = (float*)d_out;                    // zq then hist
    float* hist = out + ZQ_ELEMS;

    float* Wt     = (float*)d_ws;                   // 16384 floats
    float* embT   = Wt + NIN * DDIM;                // 32768 floats
    float* emb_sq = embT + DDIM * KCODES;           // 512 floats

    hipLaunchKernelGGL(vq_prep, dim3(128), dim3(256), 0, stream,
                       W, emb, ind_hist, Wt, embT, emb_sq, hist);

    // 64 columns per block -> 1024 blocks of 512 (4 blocks/CU, 32 waves/CU)
    hipLaunchKernelGGL(vq_main, dim3(1024), dim3(512), 0, stream,
                       z, Wt, emb, embT, emb_sq, out, hist);
}

// Round 10
// 151.315 us; speedup vs baseline: 1.0146x; 1.0146x over previous
//
#include <hip/hip_runtime.h>

// Problem constants: B=8, N_IN=256, N=8192, D=64, K=512
#define NIN    256
#define NCOL   8192
#define DDIM   64
#define KCODES 512
#define ZQ_ELEMS (8ull * 64ull * 8192ull)    // zq floats; hist follows

// ---------------------------------------------------------------------------
// Prep: Wt[i][d] = W[d][i] (conv s_loads contiguous); embT[d][k] = emb[k][d]
// (search s_loads contiguous in k); emb_sq[k] = ||emb[k]||^2 (ascending-d);
// hist_out = ind_hist (re-init every call).
// ---------------------------------------------------------------------------
__global__ __launch_bounds__(256) void vq_prep(const float* __restrict__ W,
                                               const float* __restrict__ emb,
                                               const float* __restrict__ ind_hist,
                                               float* __restrict__ Wt,
                                               float* __restrict__ embT,
                                               float* __restrict__ emb_sq,
                                               float* __restrict__ hist_out)
{
    const int t = blockIdx.x * 256 + threadIdx.x;   // t < 32768
    if (t < NIN * DDIM) {
        int i = t >> 6;
        int d = t & 63;
        Wt[t] = W[d * NIN + i];
    }
    {
        int d = t >> 9;          // 0..63
        int k = t & 511;         // 0..511
        embT[t] = emb[k * DDIM + d];
    }
    if (t < KCODES) {
        const float* __restrict__ ek = emb + t * DDIM;
        float s = 0.f;
        #pragma unroll
        for (int d = 0; d < DDIM; ++d) s = fmaf(ek[d], ek[d], s);
        emb_sq[t] = s;
        hist_out[t] = ind_hist[t];
    }
}

// ---------------------------------------------------------------------------
// Main fused kernel: block = 512 threads / 8 waves, owns 64 columns.
// 1024 blocks -> 4 blocks/CU x 8 waves = 32 waves/CU = 8 waves/SIMD.
// Round 9 post-mortem: launch_bounds(512,8) caps VGPR at 64; acc[32]+zd[8]
// (~50 live + scheduler temps) failed to color -> acc spilled to scratch
// (VGPR 32, FETCH 121 MB, WRITE 114 MB). Fix: k-tile 16 -> acc[16]+zd[8]
// ~= 30-35 live regs, trivially fits 64. Extra zd re-reads are conflict-free
// b32 at LDS stride 65 (LDS pipe ~47K cyc/CU vs 65K VALU -> not limiting).
//  conv   : wave w -> d-slice [8w,8w+8) for 64 cols (lane=col, Wt s_load,
//           ascending-i fmaf — identical to rounds 8/9).
//  search : wave w owns k-eighth [64w,64w+64), k-tiled by 16.
//           Per tile: 8 static d-chunks of 8: {8 ds_read_b32 -> zd[8], then
//           8 rows x 16 reg-reg FMAs; emb row = wave-uniform s_load of
//           embT[d][kt..kt+16)}. All register-array indices static (rule #20).
//  merge  : 8 per-wave candidates via LDS, ascending-w strict-< scan
//           == jnp.argmin first-min tie-break.
//  epilog : wave w writes zq d-slice [8w,8w+8); 1 hist atomic per column.
// ---------------------------------------------------------------------------
__global__ __launch_bounds__(512, 8) void vq_main(const float* __restrict__ z,
                                                  const float* __restrict__ Wt,
                                                  const float* __restrict__ emb,
                                                  const float* __restrict__ embT,
                                                  const float* __restrict__ emb_sq,
                                                  float* __restrict__ out,
                                                  float* __restrict__ hist)
{
    __shared__ float ze_lds[64][DDIM + 1];   // stride 65: b32 conflict-free
    __shared__ float bw_lds[8][64];
    __shared__ int   bk_lds[8][64];

    const int tid = threadIdx.x;
    const int cl  = tid & 63;                                   // column (lane)
    const int w   = __builtin_amdgcn_readfirstlane(tid >> 6);   // wave id 0..7
    const int C   = blockIdx.x * 64 + cl;
    const int b   = C >> 13;
    const int n   = C & (NCOL - 1);

    // ---------------- conv phase: wave w -> d-slice [8w, 8w+8) -------------
    {
        const float* __restrict__ zp = z + (size_t)b * NIN * NCOL + n;
        const float* __restrict__ wp = Wt + w * 8;

        float acc[8];
        #pragma unroll
        for (int j = 0; j < 8; ++j) acc[j] = 0.f;

        for (int i = 0; i < NIN; i += 4) {
            float z0 = zp[(size_t)(i + 0) * NCOL];
            float z1 = zp[(size_t)(i + 1) * NCOL];
            float z2 = zp[(size_t)(i + 2) * NCOL];
            float z3 = zp[(size_t)(i + 3) * NCOL];
            const float* __restrict__ w0 = wp + (size_t)(i + 0) * DDIM;  // s_load
            const float* __restrict__ w1 = wp + (size_t)(i + 1) * DDIM;
            const float* __restrict__ w2 = wp + (size_t)(i + 2) * DDIM;
            const float* __restrict__ w3 = wp + (size_t)(i + 3) * DDIM;
            #pragma unroll
            for (int j = 0; j < 8; ++j) {
                float a = acc[j];
                a = fmaf(w0[j], z0, a);   // ascending i
                a = fmaf(w1[j], z1, a);
                a = fmaf(w2[j], z2, a);
                a = fmaf(w3[j], z3, a);
                acc[j] = a;
            }
        }
        #pragma unroll
        for (int j = 0; j < 8; ++j) ze_lds[cl][w * 8 + j] = acc[j];
    }
    __syncthreads();

    // ---------------- zesq: ascending-d chain ------------------------------
    float zesq = 0.f;
    #pragma unroll
    for (int d = 0; d < DDIM; ++d) {
        float zd = ze_lds[cl][d];
        zesq = fmaf(zd, zd, zesq);
    }

    // ---------------- search: wave w owns k in [64w, 64w+64) ---------------
    const int k0 = w * (KCODES / 8);
    float best  = 3.4e38f;
    int   bestk = k0;

    for (int t4 = 0; t4 < 4; ++t4) {                  // 4 k-tiles of 16
        const int kt = k0 + t4 * 16;

        float acc[16];
        #pragma unroll
        for (int kk = 0; kk < 16; ++kk) acc[kk] = 0.f;

        #pragma unroll
        for (int dc = 0; dc < 8; ++dc) {              // 8 static d-chunks of 8
            float zd[8];
            #pragma unroll
            for (int j = 0; j < 8; ++j)
                zd[j] = ze_lds[cl][dc * 8 + j];       // static idx: VGPR

            #pragma unroll
            for (int j = 0; j < 8; ++j) {
                const float* __restrict__ ep =
                    embT + (size_t)(dc * 8 + j) * KCODES + kt;  // s_load x16
                #pragma unroll
                for (int kk = 0; kk < 16; ++kk)
                    acc[kk] = fmaf(ep[kk], zd[j], acc[kk]);  // ascending d
            }
        }

        #pragma unroll
        for (int kk = 0; kk < 16; ++kk) {
            const int k = kt + kk;
            float dist = (zesq + emb_sq[k]) - 2.0f * acc[kk];  // ref order
            if (dist < best) { best = dist; bestk = k; }       // first-min
        }
    }
    bw_lds[w][cl] = best;
    bk_lds[w][cl] = bestk;
    __syncthreads();

    // ---------------- merge 8 candidates (ascending w, strict <) -----------
    float fb = bw_lds[0][cl];
    int   fk = bk_lds[0][cl];
    #pragma unroll
    for (int ww = 1; ww < 8; ++ww) {
        float v = bw_lds[ww][cl];
        int  kv = bk_lds[ww][cl];
        if (v < fb) { fb = v; fk = kv; }
    }

    // ---------------- histogram: one atomic per column ---------------------
    if (w == 0) atomicAdd(hist + fk, 1.0f);

    // ---------------- straight-through output: wave w writes [8w, 8w+8) ----
    const float4* __restrict__ eb =
        reinterpret_cast<const float4*>(emb + (size_t)fk * DDIM) + w * 2;
    float* __restrict__ op = out + ((size_t)b * DDIM + w * 8) * NCOL + n;
    #pragma unroll
    for (int v = 0; v < 2; ++v) {
        float4 e = eb[v];
        float z0 = ze_lds[cl][w * 8 + 4 * v + 0];   // LDS: static indices
        float z1 = ze_lds[cl][w * 8 + 4 * v + 1];
        float z2 = ze_lds[cl][w * 8 + 4 * v + 2];
        float z3 = ze_lds[cl][w * 8 + 4 * v + 3];
        op[(size_t)(4 * v + 0) * NCOL] = z0 + (e.x - z0);
        op[(size_t)(4 * v + 1) * NCOL] = z1 + (e.y - z1);
        op[(size_t)(4 * v + 2) * NCOL] = z2 + (e.z - z2);
        op[(size_t)(4 * v + 3) * NCOL] = z3 + (e.w - z3);
    }
}

// ---------------------------------------------------------------------------
extern "C" void kernel_launch(void* const* d_in, const int* in_sizes, int n_in,
                              void* d_out, int out_size, void* d_ws, size_t ws_size,
                              hipStream_t stream)
{
    const float* z        = (const float*)d_in[0];  // (8, 256, 8192)
    const float* W        = (const float*)d_in[1];  // (64, 256)
    const float* emb      = (const float*)d_in[2];  // (512, 64)
    const float* ind_hist = (const float*)d_in[3];  // (512,)

    float* out  = (float*)d_out;                    // zq then hist
    float* hist = out + ZQ_ELEMS;

    float* Wt     = (float*)d_ws;                   // 16384 floats
    float* embT   = Wt + NIN * DDIM;                // 32768 floats
    float* emb_sq = embT + DDIM * KCODES;           // 512 floats

    hipLaunchKernelGGL(vq_prep, dim3(128), dim3(256), 0, stream,
                       W, emb, ind_hist, Wt, embT, emb_sq, hist);

    // 64 columns per block -> 1024 blocks of 512 (4 blocks/CU, 32 waves/CU)
    hipLaunchKernelGGL(vq_main, dim3(1024), dim3(512), 0, stream,
                       z, Wt, emb, embT, emb_sq, out, hist);
}